// Round 12
// baseline (147.676 us; speedup 1.0000x reference)
//
#include <hip/hip_runtime.h>
#include <math.h>

#define Bn 32
#define Cn 64
#define Ln 2048
#define NFREQ 1025
#define S0c 341
#define S1c 341
#define S2c 343
#define KPAD 352              // per-band padded K (multiple of 32, >= max band size)
#define XROW (3 * 1056)       // XS/YS row stride in u16: 3 planes x (3 bands x 352)
#define APLANE (3 * KPAD * KPAD)  // AS plane stride in u16

#define PI_D 3.14159265358979323846

typedef unsigned short u16;
typedef __attribute__((ext_vector_type(4))) u16 u16x4;
typedef __attribute__((ext_vector_type(8))) short short8;
typedef __attribute__((ext_vector_type(4))) float f32x4;

// padded LDS index: breaks power-of-2 stride bank conflicts
#define PADIX(i) ((i) + ((i) >> 4))

// round-to-nearest-even f32 -> bf16 (bit trick, exact RNE incl. mantissa carry)
__device__ __forceinline__ u16 rneb(float f) {
    unsigned u = __float_as_uint(f);
    unsigned r = (u + 0x7FFFu + ((u >> 16) & 1u)) >> 16;
    return (u16)r;
}
__device__ __forceinline__ float b2f(u16 h) {
    return __uint_as_float(((unsigned)h) << 16);
}
// exact 3-way split: v == b2f(h1)+b2f(h2)+b2f(h3) + O(2^-24 ulp)
__device__ __forceinline__ void split3(float v, u16& h1, u16& h2, u16& h3) {
    h1 = rneb(v);
    float r1 = v - b2f(h1);     // exact (Sterbenz)
    h2 = rneb(r1);
    float r2 = r1 - b2f(h2);    // exact
    h3 = rneb(r2);
}

// radix-4 digit reversal of a 10-bit index
__device__ __forceinline__ int rev4_10(unsigned x) {
    unsigned t = __brev(x) >> 22;                       // full 10-bit reversal
    return (int)(((t & 0x155u) << 1) | ((t >> 1) & 0x155u));  // un-reverse bit pairs
}

// ---------------- K1: prep = twiddles (f32) + A pre-split + YS pad zero ----------------
__global__ __launch_bounds__(256) void k_prep(const float* __restrict__ A0,
                                              const float* __restrict__ A1,
                                              const float* __restrict__ A2,
                                              float2* __restrict__ tw,
                                              u16* __restrict__ AS,
                                              u16* __restrict__ YS) {
    int b = blockIdx.x;
    int tid = threadIdx.x;
    if (b < 8) {
        int t = b * 256 + tid;
        double ang = -2.0 * PI_D * (double)t / 2048.0;
        double s, c;
        sincos(ang, &s, &c);
        tw[t] = make_float2((float)c, (float)s);   // correctly-rounded f32 twiddles
        return;
    }
    if (b < 1460) {
        int i = b - 8;                 // 0..1451 ; 484 blocks per band
        int z = i / 484;
        const float* A = (z == 0) ? A0 : ((z == 1) ? A1 : A2);
        int S = (z == 2) ? S2c : S0c;
        int idx = (i % 484) * 256 + tid;
        int d = idx / KPAD, kk = idx - d * KPAD;
        float v = (d < S && kk < S) ? A[(size_t)d * S + kk] : 0.0f;
        u16 h1, h2, h3;
        split3(v, h1, h2, h3);
        size_t o = ((size_t)z * KPAD + d) * KPAD + kk;
        AS[o] = h1;
        AS[APLANE + o] = h2;
        AS[2 * (size_t)APLANE + o] = h3;
        return;
    }
    // blocks 1460..2203: zero YS band-pad cells (2048 rows x 3 planes x 31 pads = 190,464)
    int idx = (b - 1460) * 256 + tid;
    if (idx < 2048 * 93) {
        int row = idx / 93, pr = idx - row * 93;
        int plane = pr / 31, pi = pr - plane * 31;
        int col = (pi < 11) ? (341 + pi) : ((pi < 22) ? (682 + pi) : (1025 + pi));
        YS[(size_t)row * XROW + plane * 1056 + col] = 0;
    }
}

// ---------------- K2: packed-real rfft in f32, 1 row/block ----------------
__global__ __launch_bounds__(256) void k_fft(const float* __restrict__ X,
                                             const float2* __restrict__ tw,
                                             u16* __restrict__ XS) {
    __shared__ float re[1088];
    __shared__ float im[1088];
    int row = blockIdx.x;
    int tid = threadIdx.x;
    // ---- stage 0 (Q=256) in registers from global loads ----
    {
        int k = tid;
        float2 w1 = tw[2 * k];
        float2 w2 = tw[4 * k];
        float2 w3 = tw[6 * k];
        int i0 = PADIX(k), i1 = PADIX(k + 256), i2 = PADIX(k + 512), i3 = PADIX(k + 768);
        const float2* xr = (const float2*)(X + (size_t)row * Ln);
        float2 v0 = xr[k];
        float2 v1 = xr[k + 256];
        float2 v2 = xr[k + 512];
        float2 v3 = xr[k + 768];
        float ar = v0.x, ai = v0.y;
        float br = v1.x, bi = v1.y;
        float cr = v2.x, ci = v2.y;
        float dr = v3.x, di = v3.y;
        float t0r = ar + cr, t0i = ai + ci;
        float t1r = ar - cr, t1i = ai - ci;
        float t2r = br + dr, t2i = bi + di;
        float t3r = br - dr, t3i = bi - di;
        re[i0] = t0r + t2r; im[i0] = t0i + t2i;
        float u1r = t1r + t3i, u1i = t1i - t3r;
        re[i1] = u1r * w1.x - u1i * w1.y; im[i1] = u1r * w1.y + u1i * w1.x;
        float u2r = t0r - t2r, u2i = t0i - t2i;
        re[i2] = u2r * w2.x - u2i * w2.y; im[i2] = u2r * w2.y + u2i * w2.x;
        float u3r = t1r - t3i, u3i = t1i + t3r;
        re[i3] = u3r * w3.x - u3i * w3.y; im[i3] = u3r * w3.y + u3i * w3.x;
    }
    __syncthreads();
    // ---- stages 1..4 through LDS ----
    #pragma unroll
    for (int s = 1; s < 5; ++s) {
        int log2Q = 8 - 2 * s;
        int Q = 1 << log2Q;
        int k = tid & (Q - 1);
        int g = tid >> log2Q;
        int base = (g << (log2Q + 2)) + k;
        int i0 = PADIX(base), i1 = PADIX(base + Q), i2 = PADIX(base + 2 * Q), i3 = PADIX(base + 3 * Q);
        int step = 2 << (2 * s);
        float2 w1 = tw[k * step];
        float2 w2 = tw[2 * k * step];
        float2 w3 = tw[3 * k * step];
        float ar = re[i0], ai = im[i0];
        float br = re[i1], bi = im[i1];
        float cr = re[i2], ci = im[i2];
        float dr = re[i3], di = im[i3];
        float t0r = ar + cr, t0i = ai + ci;
        float t1r = ar - cr, t1i = ai - ci;
        float t2r = br + dr, t2i = bi + di;
        float t3r = br - dr, t3i = bi - di;
        re[i0] = t0r + t2r; im[i0] = t0i + t2i;
        float u1r = t1r + t3i, u1i = t1i - t3r;
        re[i1] = u1r * w1.x - u1i * w1.y; im[i1] = u1r * w1.y + u1i * w1.x;
        float u2r = t0r - t2r, u2i = t0i - t2i;
        re[i2] = u2r * w2.x - u2i * w2.y; im[i2] = u2r * w2.y + u2i * w2.x;
        float u3r = t1r - t3i, u3i = t1i + t3r;
        re[i3] = u3r * w3.x - u3i * w3.y; im[i3] = u3r * w3.y + u3i * w3.x;
        __syncthreads();
    }
    // split: X[k] = E_k + e^{-2pi i k/2048} O_k (Z positions radix-4-digit-reversed)
    u16* xrow = XS + (size_t)row * XROW;
    if (tid < 31) {   // zero the band pad cells (341..351 | 693..703 | 1047..1055)
        int pp = (tid < 11) ? (341 + tid) : ((tid < 22) ? (682 + tid) : (1025 + tid));
        xrow[pp] = 0; xrow[1056 + pp] = 0; xrow[2112 + pp] = 0;
    }
    for (int k = tid; k <= 1024; k += 256) {
        float Xr, Xi;
        if (k == 0)        { Xr = re[0] + im[0]; Xi = 0.0f; }
        else if (k == 1024){ Xr = re[0] - im[0]; Xi = 0.0f; }
        else {
            int rv  = PADIX(rev4_10((unsigned)k));
            int rv2 = PADIX(rev4_10((unsigned)(1024 - k)));
            float2 t = tw[k];
            float Zr = re[rv],  Zi = im[rv];
            float Wr = re[rv2], Wi = im[rv2];
            float Er = 0.5f * (Zr + Wr), Ei = 0.5f * (Zi - Wi);
            float Or = 0.5f * (Zi + Wi), Oi = -0.5f * (Zr - Wr);
            Xr = Er + t.x * Or - t.y * Oi;
            Xi = Ei + t.x * Oi + t.y * Or;
        }
        float v = sqrtf(Xr * Xr + Xi * Xi);
        int zb = (k < S0c) ? 0 : ((k < S0c + S1c) ? 1 : 2);
        int pos = k + 11 * zb;   // z*352 + (k - O): band offsets 0/341/682 -> +0/+11/+22
        u16 h1, h2, h3;
        split3(v, h1, h2, h3);
        xrow[pos] = h1;
        xrow[1056 + pos] = h2;
        xrow[2112 + pos] = h3;
    }
}

// ---------------- K3: fused 3-band GEMM; epilogue emits pre-split weighted planes ----------------
// r8 geometry (proven): wave tile 32x16, block 64x32, grid (32,11,3)=1056 (~4.1/CU).
// Round-12: instead of f32 Y, the epilogue computes yw = (float)acc * sqrt(w_band) and
// stores split3 planes YS (zero-padded 1056-col layout) -> k_distdecide stages with pure
// loads (r7 lesson applied to the dist path). (float)acc is bit-identical to r10/r11's Y.
__global__ __launch_bounds__(256) void k_gemm(const u16* __restrict__ XS,
                                              const u16* __restrict__ AS,
                                              const float* __restrict__ fw,
                                              u16* __restrict__ YS) {
    const int Sarr[3] = {S0c, S1c, S2c};
    int z = blockIdx.z;
    int S = Sarr[z];

    __shared__ u16 sX1[64][40], sX2[64][40], sX3[64][40];   // X rows (stride 40: b128-aligned)
    __shared__ u16 sA1[32][40], sA2[32][40], sA3[32][40];   // A cols(d)

    int r0 = blockIdx.x * 64;
    int d0 = blockIdx.y * 32;
    int tid = threadIdx.x;
    int lane = tid & 63, w = tid >> 6;
    int wm = (w >> 1) * 32, wn = (w & 1) * 16;   // wave tile: rows [wm,wm+32), cols [wn,wn+16)
    int fm = lane & 15, kq = lane >> 4;
    int row8 = tid >> 3, seg4 = (tid & 7) * 4;   // staging: 1 row x 4 contiguous k / thread

    // softmax band weight (uniform per block; f64 math matches the r10 k_dist path)
    double f0 = (double)fw[0], f1 = (double)fw[1], f2 = (double)fw[2];
    double mfw = fmax(f0, fmax(f1, f2));
    double e0 = exp(f0 - mfw), e1 = exp(f1 - mfw), e2 = exp(f2 - mfw);
    double esum = e0 + e1 + e2;
    float swf = (z == 0) ? (float)sqrt(e0 / esum)
              : (z == 1) ? (float)sqrt(e1 / esum) : (float)sqrt(e2 / esum);

    // ---- runtime C/D layout calibration via the bf16 MFMA itself ----
    f32x4 z4 = {0.0f, 0.0f, 0.0f, 0.0f};
    short8 aone, afm;
    {
        u16 hone = 0x3F80;                 // bf16(1.0)
        u16 hfm = rneb((float)fm);         // exact for 0..15
        #pragma unroll
        for (int j = 0; j < 8; ++j) { aone[j] = (short)hone; afm[j] = (short)hfm; }
    }
    f32x4 calR = __builtin_amdgcn_mfma_f32_16x16x32_bf16(afm, aone, z4, 0, 0, 0);  // 32*row
    f32x4 calC = __builtin_amdgcn_mfma_f32_16x16x32_bf16(aone, afm, z4, 0, 0, 0);  // 32*col
    int rIdx[4], cIdx[4];
    #pragma unroll
    for (int i = 0; i < 4; ++i) {
        rIdx[i] = (int)(calR[i] * 0.03125f + 0.5f);
        cIdx[i] = (int)(calC[i] * 0.03125f + 0.5f);
    }

    // staging sources: X rows row8 and row8+32; A col-row row8 (all u16x4 8B-aligned)
    const u16* xb0 = XS + (size_t)(r0 + row8) * XROW + (size_t)z * KPAD + seg4;
    const u16* xb1 = xb0 + 32 * (size_t)XROW;
    const u16* ab  = AS + ((size_t)z * KPAD + (d0 + row8)) * KPAD + seg4;

    u16x4 wxa1, wxa2, wxa3, wxb1, wxb2, wxb3, wa1, wa2, wa3;
    auto load_tile = [&](int st) {
        int ko = st * 32;
        wxa1 = *(const u16x4*)(xb0 + ko);
        wxa2 = *(const u16x4*)(xb0 + 1056 + ko);
        wxa3 = *(const u16x4*)(xb0 + 2112 + ko);
        wxb1 = *(const u16x4*)(xb1 + ko);
        wxb2 = *(const u16x4*)(xb1 + 1056 + ko);
        wxb3 = *(const u16x4*)(xb1 + 2112 + ko);
        wa1  = *(const u16x4*)(ab + ko);
        wa2  = *(const u16x4*)(ab + APLANE + ko);
        wa3  = *(const u16x4*)(ab + 2 * (size_t)APLANE + ko);
    };

    double acc0[4] = {0.0, 0.0, 0.0, 0.0};
    double acc1[4] = {0.0, 0.0, 0.0, 0.0};
    load_tile(0);
    const int nsteps = KPAD / 32;   // 11, uniform across bands
    for (int st = 0; st < nsteps; ++st) {
        __syncthreads();
        *(u16x4*)&sX1[row8][seg4] = wxa1;
        *(u16x4*)&sX2[row8][seg4] = wxa2;
        *(u16x4*)&sX3[row8][seg4] = wxa3;
        *(u16x4*)&sX1[row8 + 32][seg4] = wxb1;
        *(u16x4*)&sX2[row8 + 32][seg4] = wxb2;
        *(u16x4*)&sX3[row8 + 32][seg4] = wxb3;
        *(u16x4*)&sA1[row8][seg4] = wa1;
        *(u16x4*)&sA2[row8][seg4] = wa2;
        *(u16x4*)&sA3[row8][seg4] = wa3;
        __syncthreads();
        if (st + 1 < nsteps) load_tile(st + 1);
        short8 b1 = *(const short8*)&sA1[wn + fm][kq * 8];
        short8 b2 = *(const short8*)&sA2[wn + fm][kq * 8];
        short8 b3 = *(const short8*)&sA3[wn + fm][kq * 8];
        {   // row-subtile 0: rows wm..wm+15
            short8 a1 = *(const short8*)&sX1[wm + fm][kq * 8];
            short8 a2 = *(const short8*)&sX2[wm + fm][kq * 8];
            short8 a3 = *(const short8*)&sX3[wm + fm][kq * 8];
            f32x4 p1 = __builtin_amdgcn_mfma_f32_16x16x32_bf16(a1, b1, z4, 0, 0, 0);
            f32x4 p2 = __builtin_amdgcn_mfma_f32_16x16x32_bf16(a1, b2, z4, 0, 0, 0);
            p2 = __builtin_amdgcn_mfma_f32_16x16x32_bf16(a2, b1, p2, 0, 0, 0);
            p2 = __builtin_amdgcn_mfma_f32_16x16x32_bf16(a1, b3, p2, 0, 0, 0);
            p2 = __builtin_amdgcn_mfma_f32_16x16x32_bf16(a2, b2, p2, 0, 0, 0);
            p2 = __builtin_amdgcn_mfma_f32_16x16x32_bf16(a3, b1, p2, 0, 0, 0);
            #pragma unroll
            for (int i = 0; i < 4; ++i) acc0[i] += (double)p1[i] + (double)p2[i];
        }
        {   // row-subtile 1: rows wm+16..wm+31
            short8 a1 = *(const short8*)&sX1[wm + 16 + fm][kq * 8];
            short8 a2 = *(const short8*)&sX2[wm + 16 + fm][kq * 8];
            short8 a3 = *(const short8*)&sX3[wm + 16 + fm][kq * 8];
            f32x4 p1 = __builtin_amdgcn_mfma_f32_16x16x32_bf16(a1, b1, z4, 0, 0, 0);
            f32x4 p2 = __builtin_amdgcn_mfma_f32_16x16x32_bf16(a1, b2, z4, 0, 0, 0);
            p2 = __builtin_amdgcn_mfma_f32_16x16x32_bf16(a2, b1, p2, 0, 0, 0);
            p2 = __builtin_amdgcn_mfma_f32_16x16x32_bf16(a1, b3, p2, 0, 0, 0);
            p2 = __builtin_amdgcn_mfma_f32_16x16x32_bf16(a2, b2, p2, 0, 0, 0);
            p2 = __builtin_amdgcn_mfma_f32_16x16x32_bf16(a3, b1, p2, 0, 0, 0);
            #pragma unroll
            for (int i = 0; i < 4; ++i) acc1[i] += (double)p1[i] + (double)p2[i];
        }
    }
    // epilogue: weighted + pre-split store (yv = (float)acc is bit-identical to r10's Y)
    #pragma unroll
    for (int i = 0; i < 4; ++i) {
        int d = d0 + wn + cIdx[i];
        if (d < S) {
            int ra = r0 + wm + rIdx[i];
            float ya = (float)acc0[i] * swf;
            float yb = (float)acc1[i] * swf;
            u16 h1, h2, h3;
            size_t oa = (size_t)ra * XROW + (size_t)z * KPAD + d;
            split3(ya, h1, h2, h3);
            YS[oa] = h1; YS[oa + 1056] = h2; YS[oa + 2112] = h3;
            size_t ob = oa + 16 * (size_t)XROW;
            split3(yb, h1, h2, h3);
            YS[ob] = h1; YS[ob + 1056] = h2; YS[ob + 2112] = h3;
        }
    }
}

// ---------------- K4: fused Gram + gumbel decision (round-12: pre-split, 1 block/batch) ----------------
// grid (32); block 256 = 4 waves. Stage batch rows ONCE from pre-split YS (pure u16x4
// loads, zero VALU); wave w computes col-tile [16w,16w+16) x 4 row-tiles -> full 64x64
// Gram in LDS (per-element MFMA sequence bit-identical to r11); q[i] = G[i][i]
// (consistent ~1e-7 error class; dist_ii == 0 exactly); decision for all 64 rows in-block.
__global__ __launch_bounds__(256) void k_distdecide(const u16* __restrict__ YS,
                                                    const float* __restrict__ gum,
                                                    float* __restrict__ out) {
    __shared__ u16 sY1[64][40], sY2[64][40], sY3[64][40];   // staged planes (15,360 B)
    __shared__ double sG[64][66];                           // full Gram (33,792 B)
    __shared__ double qv[64];
    int b = blockIdx.x;
    int tid = threadIdx.x;
    int lane = tid & 63, w = tid >> 6;
    int fm = lane & 15, kq = lane >> 4;
    int r = tid >> 3, seg = (tid & 7) * 4;    // staging: rows r, r+32; k seg..seg+3

    // ---- runtime C/D layout calibration ----
    f32x4 z4 = {0.0f, 0.0f, 0.0f, 0.0f};
    short8 aone, afm;
    {
        u16 hone = 0x3F80;
        u16 hfm = rneb((float)fm);
        #pragma unroll
        for (int j = 0; j < 8; ++j) { aone[j] = (short)hone; afm[j] = (short)hfm; }
    }
    f32x4 calR = __builtin_amdgcn_mfma_f32_16x16x32_bf16(afm, aone, z4, 0, 0, 0);
    f32x4 calC = __builtin_amdgcn_mfma_f32_16x16x32_bf16(aone, afm, z4, 0, 0, 0);
    int rIdx[4], cIdx[4];
    #pragma unroll
    for (int i = 0; i < 4; ++i) {
        rIdx[i] = (int)(calR[i] * 0.03125f + 0.5f);
        cIdx[i] = (int)(calC[i] * 0.03125f + 0.5f);
    }

    const u16* yb0 = YS + (size_t)(b * 64 + r) * XROW + seg;
    const u16* yb1 = yb0 + 32 * (size_t)XROW;
    u16x4 wa1, wa2, wa3, wb1, wb2, wb3;
    auto load_tile = [&](int st) {
        int ko = st * 32;
        wa1 = *(const u16x4*)(yb0 + ko);
        wa2 = *(const u16x4*)(yb0 + 1056 + ko);
        wa3 = *(const u16x4*)(yb0 + 2112 + ko);
        wb1 = *(const u16x4*)(yb1 + ko);
        wb2 = *(const u16x4*)(yb1 + 1056 + ko);
        wb3 = *(const u16x4*)(yb1 + 2112 + ko);
    };

    double acc[4][4] = {{0.0,0.0,0.0,0.0},{0.0,0.0,0.0,0.0},{0.0,0.0,0.0,0.0},{0.0,0.0,0.0,0.0}};
    load_tile(0);
    const int nsteps = 33;   // 33*32 = 1056 (pads zeroed by k_prep)
    for (int st = 0; st < nsteps; ++st) {
        __syncthreads();
        *(u16x4*)&sY1[r][seg] = wa1;
        *(u16x4*)&sY2[r][seg] = wa2;
        *(u16x4*)&sY3[r][seg] = wa3;
        *(u16x4*)&sY1[r + 32][seg] = wb1;
        *(u16x4*)&sY2[r + 32][seg] = wb2;
        *(u16x4*)&sY3[r + 32][seg] = wb3;
        __syncthreads();
        if (st + 1 < nsteps) load_tile(st + 1);
        short8 b1 = *(const short8*)&sY1[w * 16 + fm][kq * 8];
        short8 b2 = *(const short8*)&sY2[w * 16 + fm][kq * 8];
        short8 b3 = *(const short8*)&sY3[w * 16 + fm][kq * 8];
        #pragma unroll
        for (int t = 0; t < 4; ++t) {
            short8 a1 = *(const short8*)&sY1[t * 16 + fm][kq * 8];
            short8 a2 = *(const short8*)&sY2[t * 16 + fm][kq * 8];
            short8 a3 = *(const short8*)&sY3[t * 16 + fm][kq * 8];
            f32x4 p1 = __builtin_amdgcn_mfma_f32_16x16x32_bf16(a1, b1, z4, 0, 0, 0);
            f32x4 p2 = __builtin_amdgcn_mfma_f32_16x16x32_bf16(a1, b2, z4, 0, 0, 0);
            p2 = __builtin_amdgcn_mfma_f32_16x16x32_bf16(a2, b1, p2, 0, 0, 0);
            p2 = __builtin_amdgcn_mfma_f32_16x16x32_bf16(a1, b3, p2, 0, 0, 0);
            p2 = __builtin_amdgcn_mfma_f32_16x16x32_bf16(a2, b2, p2, 0, 0, 0);
            p2 = __builtin_amdgcn_mfma_f32_16x16x32_bf16(a3, b1, p2, 0, 0, 0);
            #pragma unroll
            for (int i = 0; i < 4; ++i) acc[t][i] += (double)p1[i] + (double)p2[i];
        }
    }
    #pragma unroll
    for (int t = 0; t < 4; ++t)
        #pragma unroll
        for (int i = 0; i < 4; ++i)
            sG[t * 16 + rIdx[i]][w * 16 + cIdx[i]] = acc[t][i];
    __syncthreads();
    if (tid < 64) qv[tid] = sG[tid][tid];
    __syncthreads();

    // ---- decision: 16 passes of 4 rows x 64 cols ----
    const float* gb = gum + (size_t)b * 8192;
    float* ob = out + (size_t)b * 4096;
    #pragma unroll
    for (int pass = 0; pass < 16; ++pass) {
        int i = pass * 4 + (tid >> 6);
        int j = tid & 63;
        double g = sG[i][j];
        double dist = fmax(qv[i] + qv[j] - 2.0 * g, 0.0);
        double e = (i == j) ? 0.0 : 1.0 / (dist + 1e-10);
        double emax = e;
        #pragma unroll
        for (int off = 32; off; off >>= 1)
            emax = fmax(emax, __shfl_xor(emax, off, 64));
        double p = (i == j) ? 0.99 : (e / emax) * 0.99;
        double l0 = log(p / (1.0 - p));
        int idx = i * 64 + j;
        double y0 = l0 + (double)gb[2 * idx];
        double y1 = -l0 + (double)gb[2 * idx + 1];
        ob[idx] = (y0 >= y1) ? 1.0f : 0.0f;   // ST == one-hot exactly
    }
}

// ---------------- launcher ----------------
extern "C" void kernel_launch(void* const* d_in, const int* in_sizes, int n_in,
                              void* d_out, int out_size, void* d_ws, size_t ws_size,
                              hipStream_t stream) {
    const float* X  = (const float*)d_in[0];
    const float* A0 = (const float*)d_in[1];
    const float* A1 = (const float*)d_in[2];
    const float* A2 = (const float*)d_in[3];
    const float* fw = (const float*)d_in[4];
    const float* gm = (const float*)d_in[5];
    float* out = (float*)d_out;

    char* ws = (char*)d_ws;
    float2* tw = (float2*)(ws);                    // 16,384 B
    u16*  XS = (u16*)(ws + 32768);                 // 2048*3168*2 = 12,976,128 -> ends 13,008,896
    u16*  AS = (u16*)(ws + 13008896);              // 3*371712*2  =  2,230,272 -> ends 15,239,168
    u16*  YS = (u16*)(ws + 15239168);              // 2048*3168*2 = 12,976,128 -> ends 28,215,296

    k_prep<<<2204, 256, 0, stream>>>(A0, A1, A2, tw, AS, YS);
    k_fft<<<Bn * Cn, 256, 0, stream>>>(X, tw, XS);
    k_gemm<<<dim3(32, 11, 3), 256, 0, stream>>>(XS, AS, fw, YS);
    k_distdecide<<<Bn, 256, 0, stream>>>(YS, gm, out);
}

// Round 13
// 137.973 us; speedup vs baseline: 1.0703x; 1.0703x over previous
//
#include <hip/hip_runtime.h>
#include <math.h>

#define Bn 32
#define Cn 64
#define Ln 2048
#define NFREQ 1025
#define S0c 341
#define S1c 341
#define S2c 343
#define KPAD 352              // per-band padded K (multiple of 32, >= max band size)
#define XROW (3 * 1056)       // XS row stride in u16: 3 planes x (3 bands x 352)
#define APLANE (3 * KPAD * KPAD)  // AS plane stride in u16

#define PI_D 3.14159265358979323846

typedef double v4d __attribute__((ext_vector_type(4)));
typedef unsigned short u16;
typedef __attribute__((ext_vector_type(4))) u16 u16x4;
typedef __attribute__((ext_vector_type(8))) short short8;
typedef __attribute__((ext_vector_type(4))) float f32x4;

// padded LDS index: breaks power-of-2 stride bank conflicts
#define PADIX(i) ((i) + ((i) >> 4))

// round-to-nearest-even f32 -> bf16 (bit trick, exact RNE incl. mantissa carry)
__device__ __forceinline__ u16 rneb(float f) {
    unsigned u = __float_as_uint(f);
    unsigned r = (u + 0x7FFFu + ((u >> 16) & 1u)) >> 16;
    return (u16)r;
}
__device__ __forceinline__ float b2f(u16 h) {
    return __uint_as_float(((unsigned)h) << 16);
}
// exact 3-way split: v == b2f(h1)+b2f(h2)+b2f(h3) + O(2^-24 ulp)
__device__ __forceinline__ void split3(float v, u16& h1, u16& h2, u16& h3) {
    h1 = rneb(v);
    float r1 = v - b2f(h1);     // exact (Sterbenz)
    h2 = rneb(r1);
    float r2 = r1 - b2f(h2);    // exact
    h3 = rneb(r2);
}

// radix-4 digit reversal of a 10-bit index
__device__ __forceinline__ int rev4_10(unsigned x) {
    unsigned t = __brev(x) >> 22;                       // full 10-bit reversal
    return (int)(((t & 0x155u) << 1) | ((t >> 1) & 0x155u));  // un-reverse bit pairs
}

// ---------------- K1: prep = twiddle table (f32) + A pre-split (one dispatch) ----------------
__global__ __launch_bounds__(256) void k_prep(const float* __restrict__ A0,
                                              const float* __restrict__ A1,
                                              const float* __restrict__ A2,
                                              float2* __restrict__ tw,
                                              u16* __restrict__ AS) {
    int b = blockIdx.x;
    int tid = threadIdx.x;
    if (b < 8) {
        int t = b * 256 + tid;
        double ang = -2.0 * PI_D * (double)t / 2048.0;
        double s, c;
        sincos(ang, &s, &c);
        tw[t] = make_float2((float)c, (float)s);   // correctly-rounded f32 twiddles
        return;
    }
    int i = b - 8;                 // 0..1451 ; 484 blocks per band (484*256 == 352*352)
    int z = i / 484;
    const float* A = (z == 0) ? A0 : ((z == 1) ? A1 : A2);
    int S = (z == 2) ? S2c : S0c;
    int idx = (i % 484) * 256 + tid;
    int d = idx / KPAD, kk = idx - d * KPAD;
    float v = (d < S && kk < S) ? A[(size_t)d * S + kk] : 0.0f;
    u16 h1, h2, h3;
    split3(v, h1, h2, h3);
    size_t o = ((size_t)z * KPAD + d) * KPAD + kk;
    AS[o] = h1;
    AS[APLANE + o] = h2;
    AS[2 * (size_t)APLANE + o] = h3;
}

// ---------------- K2: packed-real rfft in f32, 1 row/block ----------------
// f32 internals (reference computes rfft in f32): error ~2-4e-7 rel, proven safe (r10).
__global__ __launch_bounds__(256) void k_fft(const float* __restrict__ X,
                                             const float2* __restrict__ tw,
                                             u16* __restrict__ XS) {
    __shared__ float re[1088];
    __shared__ float im[1088];
    int row = blockIdx.x;
    int tid = threadIdx.x;
    // ---- stage 0 (Q=256) in registers from global loads ----
    {
        int k = tid;
        float2 w1 = tw[2 * k];
        float2 w2 = tw[4 * k];
        float2 w3 = tw[6 * k];
        int i0 = PADIX(k), i1 = PADIX(k + 256), i2 = PADIX(k + 512), i3 = PADIX(k + 768);
        const float2* xr = (const float2*)(X + (size_t)row * Ln);
        float2 v0 = xr[k];
        float2 v1 = xr[k + 256];
        float2 v2 = xr[k + 512];
        float2 v3 = xr[k + 768];
        float ar = v0.x, ai = v0.y;
        float br = v1.x, bi = v1.y;
        float cr = v2.x, ci = v2.y;
        float dr = v3.x, di = v3.y;
        float t0r = ar + cr, t0i = ai + ci;
        float t1r = ar - cr, t1i = ai - ci;
        float t2r = br + dr, t2i = bi + di;
        float t3r = br - dr, t3i = bi - di;
        re[i0] = t0r + t2r; im[i0] = t0i + t2i;
        float u1r = t1r + t3i, u1i = t1i - t3r;
        re[i1] = u1r * w1.x - u1i * w1.y; im[i1] = u1r * w1.y + u1i * w1.x;
        float u2r = t0r - t2r, u2i = t0i - t2i;
        re[i2] = u2r * w2.x - u2i * w2.y; im[i2] = u2r * w2.y + u2i * w2.x;
        float u3r = t1r - t3i, u3i = t1i + t3r;
        re[i3] = u3r * w3.x - u3i * w3.y; im[i3] = u3r * w3.y + u3i * w3.x;
    }
    __syncthreads();
    // ---- stages 1..4 through LDS ----
    #pragma unroll
    for (int s = 1; s < 5; ++s) {
        int log2Q = 8 - 2 * s;
        int Q = 1 << log2Q;
        int k = tid & (Q - 1);
        int g = tid >> log2Q;
        int base = (g << (log2Q + 2)) + k;
        int i0 = PADIX(base), i1 = PADIX(base + Q), i2 = PADIX(base + 2 * Q), i3 = PADIX(base + 3 * Q);
        int step = 2 << (2 * s);
        float2 w1 = tw[k * step];
        float2 w2 = tw[2 * k * step];
        float2 w3 = tw[3 * k * step];
        float ar = re[i0], ai = im[i0];
        float br = re[i1], bi = im[i1];
        float cr = re[i2], ci = im[i2];
        float dr = re[i3], di = im[i3];
        float t0r = ar + cr, t0i = ai + ci;
        float t1r = ar - cr, t1i = ai - ci;
        float t2r = br + dr, t2i = bi + di;
        float t3r = br - dr, t3i = bi - di;
        re[i0] = t0r + t2r; im[i0] = t0i + t2i;
        float u1r = t1r + t3i, u1i = t1i - t3r;
        re[i1] = u1r * w1.x - u1i * w1.y; im[i1] = u1r * w1.y + u1i * w1.x;
        float u2r = t0r - t2r, u2i = t0i - t2i;
        re[i2] = u2r * w2.x - u2i * w2.y; im[i2] = u2r * w2.y + u2i * w2.x;
        float u3r = t1r - t3i, u3i = t1i + t3r;
        re[i3] = u3r * w3.x - u3i * w3.y; im[i3] = u3r * w3.y + u3i * w3.x;
        __syncthreads();
    }
    // split: X[k] = E_k + e^{-2pi i k/2048} O_k (Z positions radix-4-digit-reversed)
    u16* xrow = XS + (size_t)row * XROW;
    if (tid < 31) {   // zero the band pad cells (341..351 | 693..703 | 1047..1055)
        int pp = (tid < 11) ? (341 + tid) : ((tid < 22) ? (682 + tid) : (1025 + tid));
        xrow[pp] = 0; xrow[1056 + pp] = 0; xrow[2112 + pp] = 0;
    }
    for (int k = tid; k <= 1024; k += 256) {
        float Xr, Xi;
        if (k == 0)        { Xr = re[0] + im[0]; Xi = 0.0f; }
        else if (k == 1024){ Xr = re[0] - im[0]; Xi = 0.0f; }
        else {
            int rv  = PADIX(rev4_10((unsigned)k));
            int rv2 = PADIX(rev4_10((unsigned)(1024 - k)));
            float2 t = tw[k];
            float Zr = re[rv],  Zi = im[rv];
            float Wr = re[rv2], Wi = im[rv2];
            float Er = 0.5f * (Zr + Wr), Ei = 0.5f * (Zi - Wi);
            float Or = 0.5f * (Zi + Wi), Oi = -0.5f * (Zr - Wr);
            Xr = Er + t.x * Or - t.y * Oi;
            Xi = Ei + t.x * Oi + t.y * Or;
        }
        float v = sqrtf(Xr * Xr + Xi * Xi);
        int zb = (k < S0c) ? 0 : ((k < S0c + S1c) ? 1 : 2);
        int pos = k + 11 * zb;   // z*352 + (k - O): band offsets 0/341/682 -> +0/+11/+22
        u16 h1, h2, h3;
        split3(v, h1, h2, h3);
        xrow[pos] = h1;
        xrow[1056 + pos] = h2;
        xrow[2112 + pos] = h3;
    }
}

// ---------------- K3: fused 3-band GEMM via pre-split bf16 planes ----------------
// r8 geometry (proven): wave tile 32x16, block 64x32, grid (32,11,3)=1056 (~4.1/CU).
// Y stored f32 (f64 accumulate, cast at store). SESSION BEST = this r10 form (138.0 us).
// Negative results, do not retry: r1/r2 ILP-via-VGPR (-23%), r5 LDS dbuf (neutral),
// r11 dist-fusion with in-loop split (+2), r12 epilogue-scatter + 32-block dist (+10).
__global__ __launch_bounds__(256) void k_gemm(const u16* __restrict__ XS,
                                              const u16* __restrict__ AS,
                                              float* __restrict__ Y) {
    const int Sarr[3] = {S0c, S1c, S2c};
    const int Oarr[3] = {0, S0c, S0c + S1c};
    int z = blockIdx.z;
    int S = Sarr[z], O = Oarr[z];

    __shared__ u16 sX1[64][40], sX2[64][40], sX3[64][40];   // X rows (stride 40: b128-aligned)
    __shared__ u16 sA1[32][40], sA2[32][40], sA3[32][40];   // A cols(d)

    int r0 = blockIdx.x * 64;
    int d0 = blockIdx.y * 32;
    int tid = threadIdx.x;
    int lane = tid & 63, w = tid >> 6;
    int wm = (w >> 1) * 32, wn = (w & 1) * 16;   // wave tile: rows [wm,wm+32), cols [wn,wn+16)
    int fm = lane & 15, kq = lane >> 4;
    int row8 = tid >> 3, seg4 = (tid & 7) * 4;   // staging: 1 row x 4 contiguous k / thread

    // ---- runtime C/D layout calibration via the bf16 MFMA itself ----
    f32x4 z4 = {0.0f, 0.0f, 0.0f, 0.0f};
    short8 aone, afm;
    {
        u16 hone = 0x3F80;                 // bf16(1.0)
        u16 hfm = rneb((float)fm);         // exact for 0..15
        #pragma unroll
        for (int j = 0; j < 8; ++j) { aone[j] = (short)hone; afm[j] = (short)hfm; }
    }
    f32x4 calR = __builtin_amdgcn_mfma_f32_16x16x32_bf16(afm, aone, z4, 0, 0, 0);  // 32*row
    f32x4 calC = __builtin_amdgcn_mfma_f32_16x16x32_bf16(aone, afm, z4, 0, 0, 0);  // 32*col
    int rIdx[4], cIdx[4];
    #pragma unroll
    for (int i = 0; i < 4; ++i) {
        rIdx[i] = (int)(calR[i] * 0.03125f + 0.5f);
        cIdx[i] = (int)(calC[i] * 0.03125f + 0.5f);
    }

    // staging sources: X rows row8 and row8+32; A col-row row8 (all u16x4 8B-aligned)
    const u16* xb0 = XS + (size_t)(r0 + row8) * XROW + (size_t)z * KPAD + seg4;
    const u16* xb1 = xb0 + 32 * (size_t)XROW;
    const u16* ab  = AS + ((size_t)z * KPAD + (d0 + row8)) * KPAD + seg4;

    u16x4 wxa1, wxa2, wxa3, wxb1, wxb2, wxb3, wa1, wa2, wa3;
    auto load_tile = [&](int st) {
        int ko = st * 32;
        wxa1 = *(const u16x4*)(xb0 + ko);
        wxa2 = *(const u16x4*)(xb0 + 1056 + ko);
        wxa3 = *(const u16x4*)(xb0 + 2112 + ko);
        wxb1 = *(const u16x4*)(xb1 + ko);
        wxb2 = *(const u16x4*)(xb1 + 1056 + ko);
        wxb3 = *(const u16x4*)(xb1 + 2112 + ko);
        wa1  = *(const u16x4*)(ab + ko);
        wa2  = *(const u16x4*)(ab + APLANE + ko);
        wa3  = *(const u16x4*)(ab + 2 * (size_t)APLANE + ko);
    };

    double acc0[4] = {0.0, 0.0, 0.0, 0.0};
    double acc1[4] = {0.0, 0.0, 0.0, 0.0};
    load_tile(0);
    const int nsteps = KPAD / 32;   // 11, uniform across bands
    for (int st = 0; st < nsteps; ++st) {
        __syncthreads();
        *(u16x4*)&sX1[row8][seg4] = wxa1;
        *(u16x4*)&sX2[row8][seg4] = wxa2;
        *(u16x4*)&sX3[row8][seg4] = wxa3;
        *(u16x4*)&sX1[row8 + 32][seg4] = wxb1;
        *(u16x4*)&sX2[row8 + 32][seg4] = wxb2;
        *(u16x4*)&sX3[row8 + 32][seg4] = wxb3;
        *(u16x4*)&sA1[row8][seg4] = wa1;
        *(u16x4*)&sA2[row8][seg4] = wa2;
        *(u16x4*)&sA3[row8][seg4] = wa3;
        __syncthreads();
        if (st + 1 < nsteps) load_tile(st + 1);
        short8 b1 = *(const short8*)&sA1[wn + fm][kq * 8];
        short8 b2 = *(const short8*)&sA2[wn + fm][kq * 8];
        short8 b3 = *(const short8*)&sA3[wn + fm][kq * 8];
        {   // row-subtile 0: rows wm..wm+15
            short8 a1 = *(const short8*)&sX1[wm + fm][kq * 8];
            short8 a2 = *(const short8*)&sX2[wm + fm][kq * 8];
            short8 a3 = *(const short8*)&sX3[wm + fm][kq * 8];
            f32x4 p1 = __builtin_amdgcn_mfma_f32_16x16x32_bf16(a1, b1, z4, 0, 0, 0);
            f32x4 p2 = __builtin_amdgcn_mfma_f32_16x16x32_bf16(a1, b2, z4, 0, 0, 0);
            p2 = __builtin_amdgcn_mfma_f32_16x16x32_bf16(a2, b1, p2, 0, 0, 0);
            p2 = __builtin_amdgcn_mfma_f32_16x16x32_bf16(a1, b3, p2, 0, 0, 0);
            p2 = __builtin_amdgcn_mfma_f32_16x16x32_bf16(a2, b2, p2, 0, 0, 0);
            p2 = __builtin_amdgcn_mfma_f32_16x16x32_bf16(a3, b1, p2, 0, 0, 0);
            #pragma unroll
            for (int i = 0; i < 4; ++i) acc0[i] += (double)p1[i] + (double)p2[i];
        }
        {   // row-subtile 1: rows wm+16..wm+31
            short8 a1 = *(const short8*)&sX1[wm + 16 + fm][kq * 8];
            short8 a2 = *(const short8*)&sX2[wm + 16 + fm][kq * 8];
            short8 a3 = *(const short8*)&sX3[wm + 16 + fm][kq * 8];
            f32x4 p1 = __builtin_amdgcn_mfma_f32_16x16x32_bf16(a1, b1, z4, 0, 0, 0);
            f32x4 p2 = __builtin_amdgcn_mfma_f32_16x16x32_bf16(a1, b2, z4, 0, 0, 0);
            p2 = __builtin_amdgcn_mfma_f32_16x16x32_bf16(a2, b1, p2, 0, 0, 0);
            p2 = __builtin_amdgcn_mfma_f32_16x16x32_bf16(a1, b3, p2, 0, 0, 0);
            p2 = __builtin_amdgcn_mfma_f32_16x16x32_bf16(a2, b2, p2, 0, 0, 0);
            p2 = __builtin_amdgcn_mfma_f32_16x16x32_bf16(a3, b1, p2, 0, 0, 0);
            #pragma unroll
            for (int i = 0; i < 4; ++i) acc1[i] += (double)p1[i] + (double)p2[i];
        }
    }
    #pragma unroll
    for (int i = 0; i < 4; ++i) {
        int d = d0 + wn + cIdx[i];
        if (d < S) {
            Y[(size_t)(r0 + wm + rIdx[i]) * NFREQ + O + d] = (float)acc0[i];
            Y[(size_t)(r0 + wm + 16 + rIdx[i]) * NFREQ + O + d] = (float)acc1[i];
        }
    }
}

// ---------------- K4: weighted Gram partials via f64 MFMA, G = Yw Yw^T ----------------
// grid (32 batches, 8 dim-chunks); block 256 = 4 waves (2x2 quadrants of the 64x64 G).
// Y is f32 (upcast at load; f64 accumulation & LDS unchanged).
__global__ __launch_bounds__(256) void k_dist(const float* __restrict__ Y,
                                              const float* __restrict__ fw,
                                              double* __restrict__ part) {
    __shared__ double sY[64][34];   // [row][k] f64
    int b = blockIdx.x;
    int chunk = blockIdx.y;
    int dlo = chunk * 128;
    int dhi = (chunk == 7) ? NFREQ : dlo + 128;
    int tid = threadIdx.x;
    int lane = tid & 63, w = tid >> 6;
    int wm = (w >> 1) * 32, wn = (w & 1) * 32;
    int fm = lane & 15, kq = lane >> 4;
    int kl = tid & 31, rl = tid >> 5;

    double f0 = (double)fw[0], f1 = (double)fw[1], f2 = (double)fw[2];
    double m = fmax(f0, fmax(f1, f2));
    double e0 = exp(f0 - m), e1 = exp(f1 - m), e2 = exp(f2 - m);
    double esum = e0 + e1 + e2;
    double sw0 = sqrt(e0 / esum), sw1 = sqrt(e1 / esum), sw2 = sqrt(e2 / esum);

    v4d zero = {0.0, 0.0, 0.0, 0.0};
    double aval = (double)fm;
    v4d calR = __builtin_amdgcn_mfma_f64_16x16x4f64(aval, 1.0, zero, 0, 0, 0);
    v4d calC = __builtin_amdgcn_mfma_f64_16x16x4f64(1.0, aval, zero, 0, 0, 0);
    int rIdx[4], cIdx[4];
    #pragma unroll
    for (int i = 0; i < 4; ++i) {
        rIdx[i] = (int)(calR[i] * 0.25);
        cIdx[i] = (int)(calC[i] * 0.25);
    }

    const float* Yb = Y + (size_t)b * Cn * NFREQ;
    auto load_tile = [&](int k0, double* py) {
        int d = dlo + k0 + kl;
        bool dv = d < dhi;
        double sw = dv ? ((d < S0c) ? sw0 : ((d < S0c + S1c) ? sw1 : sw2)) : 0.0;
        #pragma unroll
        for (int i = 0; i < 8; ++i)
            py[i] = dv ? (double)Yb[(size_t)(rl + 8 * i) * NFREQ + d] * sw : 0.0;
    };

    v4d acc00 = zero, acc01 = zero, acc10 = zero, acc11 = zero;
    double py[8];
    load_tile(0, py);
    int nsteps = (dhi - dlo + 31) / 32;
    for (int st = 0; st < nsteps; ++st) {
        __syncthreads();
        #pragma unroll
        for (int i = 0; i < 8; ++i) sY[rl + 8 * i][kl] = py[i];
        __syncthreads();
        if (st + 1 < nsteps) load_tile((st + 1) * 32, py);
        #pragma unroll
        for (int t = 0; t < 8; ++t) {
            int k = 4 * t + kq;
            double a0 = sY[wm + fm][k];
            double a1 = sY[wm + 16 + fm][k];
            double b0 = sY[wn + fm][k];
            double b1 = sY[wn + 16 + fm][k];
            acc00 = __builtin_amdgcn_mfma_f64_16x16x4f64(a0, b0, acc00, 0, 0, 0);
            acc01 = __builtin_amdgcn_mfma_f64_16x16x4f64(a0, b1, acc01, 0, 0, 0);
            acc10 = __builtin_amdgcn_mfma_f64_16x16x4f64(a1, b0, acc10, 0, 0, 0);
            acc11 = __builtin_amdgcn_mfma_f64_16x16x4f64(a1, b1, acc11, 0, 0, 0);
        }
    }
    double* pb = part + (((size_t)b * 8 + chunk) << 12);
    #pragma unroll
    for (int i = 0; i < 4; ++i) {
        int rowA = wm + rIdx[i], rowB = rowA + 16;
        int cA = wn + cIdx[i], cB = cA + 16;
        pb[rowA * 64 + cA] = acc00[i];
        pb[rowA * 64 + cB] = acc01[i];
        pb[rowB * 64 + cA] = acc10[i];
        pb[rowB * 64 + cB] = acc11[i];
    }
}

// ---------------- K5: sum Gram partials, dist = Gii+Gjj-2Gij, gumbel decision ----------------
// grid (32 batches, 16 row-groups); block 256 = 4 waves, one wave per matrix row.
__global__ __launch_bounds__(256) void k_decide(const double* __restrict__ part,
                                                const float* __restrict__ gum,
                                                float* __restrict__ out) {
    __shared__ double sQ[64];
    int b = blockIdx.x;
    int tid = threadIdx.x;
    const double* pb = part + (((size_t)b * 8) << 12);
    if (tid < 64) {
        double q = 0.0;
        #pragma unroll
        for (int c = 0; c < 8; ++c) q += pb[((size_t)c << 12) + tid * 65];
        sQ[tid] = q;
    }
    __syncthreads();
    int i = blockIdx.y * 4 + (tid >> 6);
    int j = tid & 63;
    double g = 0.0;
    #pragma unroll
    for (int c = 0; c < 8; ++c) g += pb[((size_t)c << 12) + i * 64 + j];
    double dist = fmax(sQ[i] + sQ[j] - 2.0 * g, 0.0);
    double e = (i == j) ? 0.0 : 1.0 / (dist + 1e-10);
    double emax = e;
    #pragma unroll
    for (int off = 32; off; off >>= 1)
        emax = fmax(emax, __shfl_xor(emax, off, 64));
    double p = (i == j) ? 0.99 : (e / emax) * 0.99;
    double l0 = log(p / (1.0 - p));
    double l1 = -l0;   // log((1-p)/p) == -log(p/(1-p)) exactly; margins are >> 1 ulp
    int idx = i * 64 + j;
    const float* gb = gum + (size_t)b * 8192;
    double y0 = l0 + (double)gb[2 * idx];
    double y1 = l1 + (double)gb[2 * idx + 1];
    out[(size_t)b * 4096 + idx] = (y0 >= y1) ? 1.0f : 0.0f;  // ST == one-hot exactly
}

// ---------------- launcher ----------------
extern "C" void kernel_launch(void* const* d_in, const int* in_sizes, int n_in,
                              void* d_out, int out_size, void* d_ws, size_t ws_size,
                              hipStream_t stream) {
    const float* X  = (const float*)d_in[0];
    const float* A0 = (const float*)d_in[1];
    const float* A1 = (const float*)d_in[2];
    const float* A2 = (const float*)d_in[3];
    const float* fw = (const float*)d_in[4];
    const float* gm = (const float*)d_in[5];
    float* out = (float*)d_out;

    char* ws = (char*)d_ws;
    float2* tw = (float2*)(ws);                    // 2048*8 = 16,384 B
    u16*  XS = (u16*)(ws + 32768);                 // 2048*3168*2 = 12,976,128 B -> ends 13,008,896
    u16*  AS = (u16*)(ws + 13008896);              // 3*371712*2  =  2,230,272 B -> ends 15,239,168
    float* Y = (float*)(ws + 15239168);            // 2048*1025*4 = 8,396,800 B -> ends 23,635,968
    // part aliases XS (dead after gemm): 32*8*4096*8 = 8,388,608 B <= 12,976,128 B
    double* part = (double*)(ws + 32768);

    k_prep<<<1460, 256, 0, stream>>>(A0, A1, A2, tw, AS);
    k_fft<<<Bn * Cn, 256, 0, stream>>>(X, tw, XS);
    k_gemm<<<dim3(32, 11, 3), 256, 0, stream>>>(XS, AS, Y);
    k_dist<<<dim3(Bn, 8), 256, 0, stream>>>(Y, fw, part);
    k_decide<<<dim3(Bn, 16), 256, 0, stream>>>(part, gm, out);
}

// Round 14
// 133.983 us; speedup vs baseline: 1.1022x; 1.0298x over previous
//
#include <hip/hip_runtime.h>
#include <math.h>

#define Bn 32
#define Cn 64
#define Ln 2048
#define NFREQ 1025
#define S0c 341
#define S1c 341
#define S2c 343
#define KPAD 352              // per-band padded K (multiple of 32, >= max band size)
#define XROW (3 * 1056)       // XS row stride in u16: 3 planes x (3 bands x 352)
#define APLANE (3 * KPAD * KPAD)  // AS plane stride in u16

#define PI_D 3.14159265358979323846

typedef double v4d __attribute__((ext_vector_type(4)));
typedef unsigned short u16;
typedef __attribute__((ext_vector_type(4))) u16 u16x4;
typedef __attribute__((ext_vector_type(8))) short short8;
typedef __attribute__((ext_vector_type(4))) float f32x4;

// padded LDS index: breaks power-of-2 stride bank conflicts
#define PADIX(i) ((i) + ((i) >> 4))

// round-to-nearest-even f32 -> bf16 (bit trick, exact RNE incl. mantissa carry)
__device__ __forceinline__ u16 rneb(float f) {
    unsigned u = __float_as_uint(f);
    unsigned r = (u + 0x7FFFu + ((u >> 16) & 1u)) >> 16;
    return (u16)r;
}
__device__ __forceinline__ float b2f(u16 h) {
    return __uint_as_float(((unsigned)h) << 16);
}
// exact 3-way split: v == b2f(h1)+b2f(h2)+b2f(h3) + O(2^-24 ulp)
__device__ __forceinline__ void split3(float v, u16& h1, u16& h2, u16& h3) {
    h1 = rneb(v);
    float r1 = v - b2f(h1);     // exact (Sterbenz)
    h2 = rneb(r1);
    float r2 = r1 - b2f(h2);    // exact
    h3 = rneb(r2);
}

// radix-4 digit reversal of a 10-bit index
__device__ __forceinline__ int rev4_10(unsigned x) {
    unsigned t = __brev(x) >> 22;                       // full 10-bit reversal
    return (int)(((t & 0x155u) << 1) | ((t >> 1) & 0x155u));  // un-reverse bit pairs
}

// ---------------- K1: fused rfft + A-pre-split (round-14: one dispatch) ----------------
// blocks 0..2047: f32 rfft of one row, twiddles computed per-block into LDS
//   (angle in f64, sincosf ~1-2 ulp vs the r13 table; |XF| perturbation ~1e-7 rel —
//   the error class already accepted since r9's f32 FFT internals).
// blocks 2048..3499: split A0/A1/A2 into 3 zero-padded 352x352 bf16 planes.
// Removes one dispatch gap (~5-6 us, r4 measurement) and the separate twiddle pass;
// A-split work overlaps the FFT on idle CUs.
__global__ __launch_bounds__(256) void k_fftprep(const float* __restrict__ X,
                                                 const float* __restrict__ A0,
                                                 const float* __restrict__ A1,
                                                 const float* __restrict__ A2,
                                                 u16* __restrict__ XS,
                                                 u16* __restrict__ AS) {
    __shared__ float re[1088];
    __shared__ float im[1088];
    __shared__ float2 twl[2048];
    int blk = blockIdx.x;
    int tid = threadIdx.x;

    if (blk >= Bn * Cn) {
        // ---- A pre-split path ----
        int i = blk - Bn * Cn;         // 0..1451 ; 484 blocks per band (484*256 == 352*352)
        int z = i / 484;
        const float* A = (z == 0) ? A0 : ((z == 1) ? A1 : A2);
        int S = (z == 2) ? S2c : S0c;
        int idx = (i % 484) * 256 + tid;
        int d = idx / KPAD, kk = idx - d * KPAD;
        float v = (d < S && kk < S) ? A[(size_t)d * S + kk] : 0.0f;
        u16 h1, h2, h3;
        split3(v, h1, h2, h3);
        size_t o = ((size_t)z * KPAD + d) * KPAD + kk;
        AS[o] = h1;
        AS[APLANE + o] = h2;
        AS[2 * (size_t)APLANE + o] = h3;
        return;
    }

    // ---- FFT path ----
    int row = blk;
    // per-block twiddle table: tw[t] = e^{-2 pi i t / 2048}; angle in f64, rounded to f32
    #pragma unroll
    for (int ii = 0; ii < 8; ++ii) {
        int t = tid + 256 * ii;
        float ang = (float)(-2.0 * PI_D / 2048.0 * (double)t);
        float s, c;
        sincosf(ang, &s, &c);
        twl[t] = make_float2(c, s);
    }
    __syncthreads();
    // ---- stage 0 (Q=256) in registers from global loads ----
    {
        int k = tid;
        float2 w1 = twl[2 * k];
        float2 w2 = twl[4 * k];
        float2 w3 = twl[6 * k];
        int i0 = PADIX(k), i1 = PADIX(k + 256), i2 = PADIX(k + 512), i3 = PADIX(k + 768);
        const float2* xr = (const float2*)(X + (size_t)row * Ln);
        float2 v0 = xr[k];
        float2 v1 = xr[k + 256];
        float2 v2 = xr[k + 512];
        float2 v3 = xr[k + 768];
        float ar = v0.x, ai = v0.y;
        float br = v1.x, bi = v1.y;
        float cr = v2.x, ci = v2.y;
        float dr = v3.x, di = v3.y;
        float t0r = ar + cr, t0i = ai + ci;
        float t1r = ar - cr, t1i = ai - ci;
        float t2r = br + dr, t2i = bi + di;
        float t3r = br - dr, t3i = bi - di;
        re[i0] = t0r + t2r; im[i0] = t0i + t2i;
        float u1r = t1r + t3i, u1i = t1i - t3r;
        re[i1] = u1r * w1.x - u1i * w1.y; im[i1] = u1r * w1.y + u1i * w1.x;
        float u2r = t0r - t2r, u2i = t0i - t2i;
        re[i2] = u2r * w2.x - u2i * w2.y; im[i2] = u2r * w2.y + u2i * w2.x;
        float u3r = t1r - t3i, u3i = t1i + t3r;
        re[i3] = u3r * w3.x - u3i * w3.y; im[i3] = u3r * w3.y + u3i * w3.x;
    }
    __syncthreads();
    // ---- stages 1..4 through LDS ----
    #pragma unroll
    for (int s = 1; s < 5; ++s) {
        int log2Q = 8 - 2 * s;
        int Q = 1 << log2Q;
        int k = tid & (Q - 1);
        int g = tid >> log2Q;
        int base = (g << (log2Q + 2)) + k;
        int i0 = PADIX(base), i1 = PADIX(base + Q), i2 = PADIX(base + 2 * Q), i3 = PADIX(base + 3 * Q);
        int step = 2 << (2 * s);
        float2 w1 = twl[k * step];
        float2 w2 = twl[2 * k * step];
        float2 w3 = twl[3 * k * step];
        float ar = re[i0], ai = im[i0];
        float br = re[i1], bi = im[i1];
        float cr = re[i2], ci = im[i2];
        float dr = re[i3], di = im[i3];
        float t0r = ar + cr, t0i = ai + ci;
        float t1r = ar - cr, t1i = ai - ci;
        float t2r = br + dr, t2i = bi + di;
        float t3r = br - dr, t3i = bi - di;
        re[i0] = t0r + t2r; im[i0] = t0i + t2i;
        float u1r = t1r + t3i, u1i = t1i - t3r;
        re[i1] = u1r * w1.x - u1i * w1.y; im[i1] = u1r * w1.y + u1i * w1.x;
        float u2r = t0r - t2r, u2i = t0i - t2i;
        re[i2] = u2r * w2.x - u2i * w2.y; im[i2] = u2r * w2.y + u2i * w2.x;
        float u3r = t1r - t3i, u3i = t1i + t3r;
        re[i3] = u3r * w3.x - u3i * w3.y; im[i3] = u3r * w3.y + u3i * w3.x;
        __syncthreads();
    }
    // split: X[k] = E_k + e^{-2pi i k/2048} O_k (Z positions radix-4-digit-reversed)
    u16* xrow = XS + (size_t)row * XROW;
    if (tid < 31) {   // zero the band pad cells (341..351 | 693..703 | 1047..1055)
        int pp = (tid < 11) ? (341 + tid) : ((tid < 22) ? (682 + tid) : (1025 + tid));
        xrow[pp] = 0; xrow[1056 + pp] = 0; xrow[2112 + pp] = 0;
    }
    for (int k = tid; k <= 1024; k += 256) {
        float Xr, Xi;
        if (k == 0)        { Xr = re[0] + im[0]; Xi = 0.0f; }
        else if (k == 1024){ Xr = re[0] - im[0]; Xi = 0.0f; }
        else {
            int rv  = PADIX(rev4_10((unsigned)k));
            int rv2 = PADIX(rev4_10((unsigned)(1024 - k)));
            float2 t = twl[k];
            float Zr = re[rv],  Zi = im[rv];
            float Wr = re[rv2], Wi = im[rv2];
            float Er = 0.5f * (Zr + Wr), Ei = 0.5f * (Zi - Wi);
            float Or = 0.5f * (Zi + Wi), Oi = -0.5f * (Zr - Wr);
            Xr = Er + t.x * Or - t.y * Oi;
            Xi = Ei + t.x * Oi + t.y * Or;
        }
        float v = sqrtf(Xr * Xr + Xi * Xi);
        int zb = (k < S0c) ? 0 : ((k < S0c + S1c) ? 1 : 2);
        int pos = k + 11 * zb;   // z*352 + (k - O): band offsets 0/341/682 -> +0/+11/+22
        u16 h1, h2, h3;
        split3(v, h1, h2, h3);
        xrow[pos] = h1;
        xrow[1056 + pos] = h2;
        xrow[2112 + pos] = h3;
    }
}

// ---------------- K3: fused 3-band GEMM via pre-split bf16 planes ----------------
// r8 geometry (proven): wave tile 32x16, block 64x32, grid (32,11,3)=1056 (~4.1/CU).
// Y stored f32 (f64 accumulate, cast at store). SESSION BEST base = r10/r13 (138.0 us).
// Negative results, do not retry: r1/r2 ILP-via-VGPR (-23%), r5 LDS dbuf (neutral),
// r11 dist-fusion with in-loop split (+2), r12 epilogue-scatter + 32-block dist (+10).
__global__ __launch_bounds__(256) void k_gemm(const u16* __restrict__ XS,
                                              const u16* __restrict__ AS,
                                              float* __restrict__ Y) {
    const int Sarr[3] = {S0c, S1c, S2c};
    const int Oarr[3] = {0, S0c, S0c + S1c};
    int z = blockIdx.z;
    int S = Sarr[z], O = Oarr[z];

    __shared__ u16 sX1[64][40], sX2[64][40], sX3[64][40];   // X rows (stride 40: b128-aligned)
    __shared__ u16 sA1[32][40], sA2[32][40], sA3[32][40];   // A cols(d)

    int r0 = blockIdx.x * 64;
    int d0 = blockIdx.y * 32;
    int tid = threadIdx.x;
    int lane = tid & 63, w = tid >> 6;
    int wm = (w >> 1) * 32, wn = (w & 1) * 16;   // wave tile: rows [wm,wm+32), cols [wn,wn+16)
    int fm = lane & 15, kq = lane >> 4;
    int row8 = tid >> 3, seg4 = (tid & 7) * 4;   // staging: 1 row x 4 contiguous k / thread

    // ---- runtime C/D layout calibration via the bf16 MFMA itself ----
    f32x4 z4 = {0.0f, 0.0f, 0.0f, 0.0f};
    short8 aone, afm;
    {
        u16 hone = 0x3F80;                 // bf16(1.0)
        u16 hfm = rneb((float)fm);         // exact for 0..15
        #pragma unroll
        for (int j = 0; j < 8; ++j) { aone[j] = (short)hone; afm[j] = (short)hfm; }
    }
    f32x4 calR = __builtin_amdgcn_mfma_f32_16x16x32_bf16(afm, aone, z4, 0, 0, 0);  // 32*row
    f32x4 calC = __builtin_amdgcn_mfma_f32_16x16x32_bf16(aone, afm, z4, 0, 0, 0);  // 32*col
    int rIdx[4], cIdx[4];
    #pragma unroll
    for (int i = 0; i < 4; ++i) {
        rIdx[i] = (int)(calR[i] * 0.03125f + 0.5f);
        cIdx[i] = (int)(calC[i] * 0.03125f + 0.5f);
    }

    // staging sources: X rows row8 and row8+32; A col-row row8 (all u16x4 8B-aligned)
    const u16* xb0 = XS + (size_t)(r0 + row8) * XROW + (size_t)z * KPAD + seg4;
    const u16* xb1 = xb0 + 32 * (size_t)XROW;
    const u16* ab  = AS + ((size_t)z * KPAD + (d0 + row8)) * KPAD + seg4;

    u16x4 wxa1, wxa2, wxa3, wxb1, wxb2, wxb3, wa1, wa2, wa3;
    auto load_tile = [&](int st) {
        int ko = st * 32;
        wxa1 = *(const u16x4*)(xb0 + ko);
        wxa2 = *(const u16x4*)(xb0 + 1056 + ko);
        wxa3 = *(const u16x4*)(xb0 + 2112 + ko);
        wxb1 = *(const u16x4*)(xb1 + ko);
        wxb2 = *(const u16x4*)(xb1 + 1056 + ko);
        wxb3 = *(const u16x4*)(xb1 + 2112 + ko);
        wa1  = *(const u16x4*)(ab + ko);
        wa2  = *(const u16x4*)(ab + APLANE + ko);
        wa3  = *(const u16x4*)(ab + 2 * (size_t)APLANE + ko);
    };

    double acc0[4] = {0.0, 0.0, 0.0, 0.0};
    double acc1[4] = {0.0, 0.0, 0.0, 0.0};
    load_tile(0);
    const int nsteps = KPAD / 32;   // 11, uniform across bands
    for (int st = 0; st < nsteps; ++st) {
        __syncthreads();
        *(u16x4*)&sX1[row8][seg4] = wxa1;
        *(u16x4*)&sX2[row8][seg4] = wxa2;
        *(u16x4*)&sX3[row8][seg4] = wxa3;
        *(u16x4*)&sX1[row8 + 32][seg4] = wxb1;
        *(u16x4*)&sX2[row8 + 32][seg4] = wxb2;
        *(u16x4*)&sX3[row8 + 32][seg4] = wxb3;
        *(u16x4*)&sA1[row8][seg4] = wa1;
        *(u16x4*)&sA2[row8][seg4] = wa2;
        *(u16x4*)&sA3[row8][seg4] = wa3;
        __syncthreads();
        if (st + 1 < nsteps) load_tile(st + 1);
        short8 b1 = *(const short8*)&sA1[wn + fm][kq * 8];
        short8 b2 = *(const short8*)&sA2[wn + fm][kq * 8];
        short8 b3 = *(const short8*)&sA3[wn + fm][kq * 8];
        {   // row-subtile 0: rows wm..wm+15
            short8 a1 = *(const short8*)&sX1[wm + fm][kq * 8];
            short8 a2 = *(const short8*)&sX2[wm + fm][kq * 8];
            short8 a3 = *(const short8*)&sX3[wm + fm][kq * 8];
            f32x4 p1 = __builtin_amdgcn_mfma_f32_16x16x32_bf16(a1, b1, z4, 0, 0, 0);
            f32x4 p2 = __builtin_amdgcn_mfma_f32_16x16x32_bf16(a1, b2, z4, 0, 0, 0);
            p2 = __builtin_amdgcn_mfma_f32_16x16x32_bf16(a2, b1, p2, 0, 0, 0);
            p2 = __builtin_amdgcn_mfma_f32_16x16x32_bf16(a1, b3, p2, 0, 0, 0);
            p2 = __builtin_amdgcn_mfma_f32_16x16x32_bf16(a2, b2, p2, 0, 0, 0);
            p2 = __builtin_amdgcn_mfma_f32_16x16x32_bf16(a3, b1, p2, 0, 0, 0);
            #pragma unroll
            for (int i = 0; i < 4; ++i) acc0[i] += (double)p1[i] + (double)p2[i];
        }
        {   // row-subtile 1: rows wm+16..wm+31
            short8 a1 = *(const short8*)&sX1[wm + 16 + fm][kq * 8];
            short8 a2 = *(const short8*)&sX2[wm + 16 + fm][kq * 8];
            short8 a3 = *(const short8*)&sX3[wm + 16 + fm][kq * 8];
            f32x4 p1 = __builtin_amdgcn_mfma_f32_16x16x32_bf16(a1, b1, z4, 0, 0, 0);
            f32x4 p2 = __builtin_amdgcn_mfma_f32_16x16x32_bf16(a1, b2, z4, 0, 0, 0);
            p2 = __builtin_amdgcn_mfma_f32_16x16x32_bf16(a2, b1, p2, 0, 0, 0);
            p2 = __builtin_amdgcn_mfma_f32_16x16x32_bf16(a1, b3, p2, 0, 0, 0);
            p2 = __builtin_amdgcn_mfma_f32_16x16x32_bf16(a2, b2, p2, 0, 0, 0);
            p2 = __builtin_amdgcn_mfma_f32_16x16x32_bf16(a3, b1, p2, 0, 0, 0);
            #pragma unroll
            for (int i = 0; i < 4; ++i) acc1[i] += (double)p1[i] + (double)p2[i];
        }
    }
    #pragma unroll
    for (int i = 0; i < 4; ++i) {
        int d = d0 + wn + cIdx[i];
        if (d < S) {
            Y[(size_t)(r0 + wm + rIdx[i]) * NFREQ + O + d] = (float)acc0[i];
            Y[(size_t)(r0 + wm + 16 + rIdx[i]) * NFREQ + O + d] = (float)acc1[i];
        }
    }
}

// ---------------- K4: weighted Gram partials via f64 MFMA, G = Yw Yw^T ----------------
// grid (32 batches, 8 dim-chunks); block 256 = 4 waves (2x2 quadrants of the 64x64 G).
// Y is f32 (upcast at load; f64 accumulation & LDS unchanged).
__global__ __launch_bounds__(256) void k_dist(const float* __restrict__ Y,
                                              const float* __restrict__ fw,
                                              double* __restrict__ part) {
    __shared__ double sY[64][34];   // [row][k] f64
    int b = blockIdx.x;
    int chunk = blockIdx.y;
    int dlo = chunk * 128;
    int dhi = (chunk == 7) ? NFREQ : dlo + 128;
    int tid = threadIdx.x;
    int lane = tid & 63, w = tid >> 6;
    int wm = (w >> 1) * 32, wn = (w & 1) * 32;
    int fm = lane & 15, kq = lane >> 4;
    int kl = tid & 31, rl = tid >> 5;

    double f0 = (double)fw[0], f1 = (double)fw[1], f2 = (double)fw[2];
    double m = fmax(f0, fmax(f1, f2));
    double e0 = exp(f0 - m), e1 = exp(f1 - m), e2 = exp(f2 - m);
    double esum = e0 + e1 + e2;
    double sw0 = sqrt(e0 / esum), sw1 = sqrt(e1 / esum), sw2 = sqrt(e2 / esum);

    v4d zero = {0.0, 0.0, 0.0, 0.0};
    double aval = (double)fm;
    v4d calR = __builtin_amdgcn_mfma_f64_16x16x4f64(aval, 1.0, zero, 0, 0, 0);
    v4d calC = __builtin_amdgcn_mfma_f64_16x16x4f64(1.0, aval, zero, 0, 0, 0);
    int rIdx[4], cIdx[4];
    #pragma unroll
    for (int i = 0; i < 4; ++i) {
        rIdx[i] = (int)(calR[i] * 0.25);
        cIdx[i] = (int)(calC[i] * 0.25);
    }

    const float* Yb = Y + (size_t)b * Cn * NFREQ;
    auto load_tile = [&](int k0, double* py) {
        int d = dlo + k0 + kl;
        bool dv = d < dhi;
        double sw = dv ? ((d < S0c) ? sw0 : ((d < S0c + S1c) ? sw1 : sw2)) : 0.0;
        #pragma unroll
        for (int i = 0; i < 8; ++i)
            py[i] = dv ? (double)Yb[(size_t)(rl + 8 * i) * NFREQ + d] * sw : 0.0;
    };

    v4d acc00 = zero, acc01 = zero, acc10 = zero, acc11 = zero;
    double py[8];
    load_tile(0, py);
    int nsteps = (dhi - dlo + 31) / 32;
    for (int st = 0; st < nsteps; ++st) {
        __syncthreads();
        #pragma unroll
        for (int i = 0; i < 8; ++i) sY[rl + 8 * i][kl] = py[i];
        __syncthreads();
        if (st + 1 < nsteps) load_tile((st + 1) * 32, py);
        #pragma unroll
        for (int t = 0; t < 8; ++t) {
            int k = 4 * t + kq;
            double a0 = sY[wm + fm][k];
            double a1 = sY[wm + 16 + fm][k];
            double b0 = sY[wn + fm][k];
            double b1 = sY[wn + 16 + fm][k];
            acc00 = __builtin_amdgcn_mfma_f64_16x16x4f64(a0, b0, acc00, 0, 0, 0);
            acc01 = __builtin_amdgcn_mfma_f64_16x16x4f64(a0, b1, acc01, 0, 0, 0);
            acc10 = __builtin_amdgcn_mfma_f64_16x16x4f64(a1, b0, acc10, 0, 0, 0);
            acc11 = __builtin_amdgcn_mfma_f64_16x16x4f64(a1, b1, acc11, 0, 0, 0);
        }
    }
    double* pb = part + (((size_t)b * 8 + chunk) << 12);
    #pragma unroll
    for (int i = 0; i < 4; ++i) {
        int rowA = wm + rIdx[i], rowB = rowA + 16;
        int cA = wn + cIdx[i], cB = cA + 16;
        pb[rowA * 64 + cA] = acc00[i];
        pb[rowA * 64 + cB] = acc01[i];
        pb[rowB * 64 + cA] = acc10[i];
        pb[rowB * 64 + cB] = acc11[i];
    }
}

// ---------------- K5: sum Gram partials, dist = Gii+Gjj-2Gij, gumbel decision ----------------
// grid (32 batches, 16 row-groups); block 256 = 4 waves, one wave per matrix row.
__global__ __launch_bounds__(256) void k_decide(const double* __restrict__ part,
                                                const float* __restrict__ gum,
                                                float* __restrict__ out) {
    __shared__ double sQ[64];
    int b = blockIdx.x;
    int tid = threadIdx.x;
    const double* pb = part + (((size_t)b * 8) << 12);
    if (tid < 64) {
        double q = 0.0;
        #pragma unroll
        for (int c = 0; c < 8; ++c) q += pb[((size_t)c << 12) + tid * 65];
        sQ[tid] = q;
    }
    __syncthreads();
    int i = blockIdx.y * 4 + (tid >> 6);
    int j = tid & 63;
    double g = 0.0;
    #pragma unroll
    for (int c = 0; c < 8; ++c) g += pb[((size_t)c << 12) + i * 64 + j];
    double dist = fmax(sQ[i] + sQ[j] - 2.0 * g, 0.0);
    double e = (i == j) ? 0.0 : 1.0 / (dist + 1e-10);
    double emax = e;
    #pragma unroll
    for (int off = 32; off; off >>= 1)
        emax = fmax(emax, __shfl_xor(emax, off, 64));
    double p = (i == j) ? 0.99 : (e / emax) * 0.99;
    double l0 = log(p / (1.0 - p));
    double l1 = -l0;   // log((1-p)/p) == -log(p/(1-p)) exactly; margins are >> 1 ulp
    int idx = i * 64 + j;
    const float* gb = gum + (size_t)b * 8192;
    double y0 = l0 + (double)gb[2 * idx];
    double y1 = l1 + (double)gb[2 * idx + 1];
    out[(size_t)b * 4096 + idx] = (y0 >= y1) ? 1.0f : 0.0f;  // ST == one-hot exactly
}

// ---------------- launcher ----------------
extern "C" void kernel_launch(void* const* d_in, const int* in_sizes, int n_in,
                              void* d_out, int out_size, void* d_ws, size_t ws_size,
                              hipStream_t stream) {
    const float* X  = (const float*)d_in[0];
    const float* A0 = (const float*)d_in[1];
    const float* A1 = (const float*)d_in[2];
    const float* A2 = (const float*)d_in[3];
    const float* fw = (const float*)d_in[4];
    const float* gm = (const float*)d_in[5];
    float* out = (float*)d_out;

    char* ws = (char*)d_ws;
    u16*  XS = (u16*)(ws + 32768);                 // 2048*3168*2 = 12,976,128 B -> ends 13,008,896
    u16*  AS = (u16*)(ws + 13008896);              // 3*371712*2  =  2,230,272 B -> ends 15,239,168
    float* Y = (float*)(ws + 15239168);            // 2048*1025*4 = 8,396,800 B -> ends 23,635,968
    // part aliases XS (dead after gemm): 32*8*4096*8 = 8,388,608 B <= 12,976,128 B
    double* part = (double*)(ws + 32768);

    k_fftprep<<<Bn * Cn + 1452, 256, 0, stream>>>(X, A0, A1, A2, XS, AS);
    k_gemm<<<dim3(32, 11, 3), 256, 0, stream>>>(XS, AS, Y);
    k_dist<<<dim3(Bn, 8), 256, 0, stream>>>(Y, fw, part);
    k_decide<<<dim3(Bn, 16), 256, 0, stream>>>(part, gm, out);
}